// Round 4
// baseline (1487.194 us; speedup 1.0000x reference)
//
#include <hip/hip_runtime.h>
#include <hip/hip_bf16.h>
#include <math.h>

#define BB 8
#define NN 4096
#define NIN 64
#define NOUTF 128
#define KNB 32
#define MM 1024
#define DIM 68
#define CAP 320

typedef float f32x2 __attribute__((ext_vector_type(2)));

__device__ __forceinline__ f32x2 pkmin(f32x2 a, f32x2 b)
{
    f32x2 r; r.x = fminf(a.x, b.x); r.y = fminf(a.y, b.y); return r;
}
__device__ __forceinline__ f32x2 pkmax(f32x2 a, f32x2 b)
{
    f32x2 r; r.x = fmaxf(a.x, b.x); r.y = fmaxf(a.y, b.y); return r;
}

// DPP max-reduce step: v = max(v, lanes-moved-v). CTRL compile-time.
template <int CTRL>
__device__ __forceinline__ float dppmax(float v)
{
    int m = __builtin_amdgcn_update_dpp(__float_as_int(v), __float_as_int(v),
                                        CTRL, 0xF, 0xF, false);
    return fmaxf(v, __int_as_float(m));
}

// ---------------------------------------------------------------------------
// Kernel 1: farthest point sampling. One block per batch, serial over M steps.
// Exact-match constraints: no FMA contraction, (dx*dx+dy*dy)+dz*dz order,
// argmax = first occurrence (max value, then min global index).
// 512 threads x 8 points, thread-major (p = tid*8 + k): lane/wave order ==
// global index order. Hot loop is max-only; the winner thread recovers its
// local argmax afterwards (exec-masked to one wave).
// ---------------------------------------------------------------------------
__global__ __launch_bounds__(512) void fps_kernel(
    const float* __restrict__ pos,
    int* __restrict__ idx_ws, float* __restrict__ pos_s_ws,
    float* __restrict__ out_pos_s, float* __restrict__ out_idx)
{
#pragma clang fp contract(off)
    __shared__ float4 redP[2][8];   // {x, y, z, val} per wave, double-buffered
    __shared__ int    redN[2][8];   // idx per wave

    const int b    = blockIdx.x;
    const int tid  = threadIdx.x;
    const int wv   = tid >> 6;
    const int lane = tid & 63;
    const float* pb = pos + (size_t)b * NN * 3;

    // 8 consecutive points per thread: p = tid*8 + k.
    // Packed pairs: X[j].x <-> k=2j, X[j].y <-> k=2j+1.
    f32x2 X[4], Y[4], Z[4], D[4];
#pragma unroll
    for (int j = 0; j < 4; ++j) {
        int pA = tid * 8 + 2 * j;
        X[j].x = pb[pA * 3 + 0]; X[j].y = pb[pA * 3 + 3];
        Y[j].x = pb[pA * 3 + 1]; Y[j].y = pb[pA * 3 + 4];
        Z[j].x = pb[pA * 3 + 2]; Z[j].y = pb[pA * 3 + 5];
        D[j].x = INFINITY;       D[j].y = INFINITY;
    }

    int   last = 0;
    float lx = pb[0], ly = pb[1], lz = pb[2];

    for (int t = 0; t < MM; ++t) {
        // emit current sample from registers
        if (tid == 0) {
            idx_ws[b * MM + t]  = last;
            out_idx[b * MM + t] = (float)last;
            pos_s_ws[(b * MM + t) * 3 + 0] = lx;
            pos_s_ws[(b * MM + t) * 3 + 1] = ly;
            pos_s_ws[(b * MM + t) * 3 + 2] = lz;
            out_pos_s[(b * MM + t) * 3 + 0] = lx;
            out_pos_s[(b * MM + t) * 3 + 1] = ly;
            out_pos_s[(b * MM + t) * 3 + 2] = lz;
        }

        f32x2 lx2; lx2.x = lx; lx2.y = lx;
        f32x2 ly2; ly2.x = ly; ly2.y = ly;
        f32x2 lz2; lz2.x = lz; lz2.y = lz;

        // pure min-update + max-tree scan (no argmax tracking)
#pragma unroll
        for (int j = 0; j < 4; ++j) {
            f32x2 dx = X[j] - lx2;
            f32x2 dy = Y[j] - ly2;
            f32x2 dz = Z[j] - lz2;
            f32x2 s  = (dx * dx + dy * dy) + dz * dz;   // contract off => exact
            D[j] = pkmin(D[j], s);
        }
        f32x2 m01 = pkmax(D[0], D[1]);
        f32x2 m23 = pkmax(D[2], D[3]);
        f32x2 mm  = pkmax(m01, m23);
        float bv  = fmaxf(mm.x, mm.y);

        // VALU-speed wave max-reduce: row_shr 1/2/4/8, row_bcast 15/31
        float r = bv;
        r = dppmax<0x111>(r);
        r = dppmax<0x112>(r);
        r = dppmax<0x114>(r);
        r = dppmax<0x118>(r);
        r = dppmax<0x142>(r);
        r = dppmax<0x143>(r);
        float wmax = __int_as_float(__builtin_amdgcn_readlane(__float_as_int(r), 63));

        // winner = lowest lane matching wmax (== smallest global index)
        unsigned long long msk = __ballot(bv == wmax);
        int wl = __ffsll(msk) - 1;

        const int p_ = t & 1;
        if (lane == wl) {
            // recover smallest k with D==bv (descending scan: last write = min k)
            int k = 7;
            if (D[3].y == bv) k = 7;
            if (D[3].x == bv) k = 6;
            if (D[2].y == bv) k = 5;
            if (D[2].x == bv) k = 4;
            if (D[1].y == bv) k = 3;
            if (D[1].x == bv) k = 2;
            if (D[0].y == bv) k = 1;
            if (D[0].x == bv) k = 0;
            int jj = k >> 1;

            f32x2 xa = (jj & 1) ? X[1] : X[0];
            f32x2 xb = (jj & 1) ? X[3] : X[2];
            f32x2 xe = (jj & 2) ? xb : xa;
            float bx = (k & 1) ? xe.y : xe.x;

            f32x2 ya = (jj & 1) ? Y[1] : Y[0];
            f32x2 yb = (jj & 1) ? Y[3] : Y[2];
            f32x2 ye = (jj & 2) ? yb : ya;
            float by = (k & 1) ? ye.y : ye.x;

            f32x2 za = (jj & 1) ? Z[1] : Z[0];
            f32x2 zb = (jj & 1) ? Z[3] : Z[2];
            f32x2 ze = (jj & 2) ? zb : za;
            float bz = (k & 1) ? ze.y : ze.x;

            redP[p_][wv] = make_float4(bx, by, bz, bv);
            redN[p_][wv] = tid * 8 + k;
        }
        __syncthreads();   // single barrier per iteration (double-buffered)

        // 8-slot merge: reads issue independently, then dependent select chain
        float4 e0 = redP[p_][0];
        float cv = e0.w; int ci = redN[p_][0];
        float cx = e0.x, cy = e0.y, cz = e0.z;
#pragma unroll
        for (int w = 1; w < 8; ++w) {
            float4 ew = redP[p_][w]; int iw = redN[p_][w];
            bool bt = (ew.w > cv) || (ew.w == cv && iw < ci);
            cv = bt ? ew.w : cv; ci = bt ? iw : ci;
            cx = bt ? ew.x : cx; cy = bt ? ew.y : cy; cz = bt ? ew.z : cz;
        }
        last = ci; lx = cx; ly = cy; lz = cz;
    }
}

// ---------------------------------------------------------------------------
// Kernel 2: radius search + exact K-smallest selection. One wave per center.
// ---------------------------------------------------------------------------
__global__ __launch_bounds__(256) void radius_kernel(
    const float* __restrict__ pos,
    const float* __restrict__ pos_s_ws,
    int* __restrict__ nbr_ws, int* __restrict__ nvalid_ws)
{
    __shared__ float d2L[4][CAP];
    __shared__ int   idL[4][CAP];
    __shared__ int   cntL[4];

    const int wv = threadIdx.x >> 6, lane = threadIdx.x & 63;
    const int c = blockIdx.x * 4 + wv;
    const int b = c >> 10;
    const float RSQ = 0.0225f;

    if (lane == 0) cntL[wv] = 0;

    float cx = pos_s_ws[c * 3 + 0];
    float cy = pos_s_ws[c * 3 + 1];
    float cz = pos_s_ws[c * 3 + 2];
    const float* pb = pos + (size_t)b * NN * 3;

    for (int it = 0; it < NN / 64; ++it) {
        int p = it * 64 + lane;
        float dx = __fsub_rn(cx, pb[p * 3 + 0]);
        float dy = __fsub_rn(cy, pb[p * 3 + 1]);
        float dz = __fsub_rn(cz, pb[p * 3 + 2]);
        float d2 = __fadd_rn(__fadd_rn(__fmul_rn(dx, dx), __fmul_rn(dy, dy)),
                             __fmul_rn(dz, dz));
        if (d2 <= RSQ) {
            int slot = atomicAdd(&cntL[wv], 1);
            if (slot < CAP) { d2L[wv][slot] = d2; idL[wv][slot] = p; }
        }
    }
    int n = cntL[wv];
    if (n > CAP) n = CAP;

    if (n <= KNB) {
        if (lane == 0) nvalid_ws[c] = n;
        if (lane < n) nbr_ws[c * KNB + lane] = idL[wv][lane];
    } else {
        if (lane == 0) nvalid_ws[c] = KNB;
        for (int a = lane; a < n; a += 64) {
            float da = d2L[wv][a]; int ia = idL[wv][a];
            int r = 0;
            for (int jj = 0; jj < n; ++jj) {
                float dj = d2L[wv][jj]; int ij = idL[wv][jj];
                r += (dj < da || (dj == da && ij < ia)) ? 1 : 0;
            }
            if (r < KNB) nbr_ws[c * KNB + r] = ia;
        }
    }
}

// ---------------------------------------------------------------------------
// Kernel 3: message build (x_j ++ ppf) -> 68x68 MLP x2 -> masked max-agg ->
// 68x128 output matvec. Block = 2 centers (64 edges), weights in LDS.
// ---------------------------------------------------------------------------
__device__ __forceinline__ float angle3(float ax, float ay, float az,
                                        float bx, float by, float bz)
{
    float cx = ay * bz - az * by;
    float cy = az * bx - ax * bz;
    float cz = ax * by - ay * bx;
    float cn = sqrtf(cx * cx + cy * cy + cz * cz);
    float dt = ax * bx + ay * by + az * bz;
    return atan2f(cn, dt);
}

__device__ __forceinline__ void layer_pass(const float* __restrict__ inL,
                                           const float* __restrict__ Ws,
                                           const float* __restrict__ bs,
                                           float* __restrict__ outL, int t)
{
    const int e = t & 63, wvi = t >> 6;
    for (int jg = wvi; jg < 17; jg += 4) {
        float ax = bs[jg * 4 + 0];
        float ay = bs[jg * 4 + 1];
        float az = bs[jg * 4 + 2];
        float aw = bs[jg * 4 + 3];
#pragma unroll 4
        for (int i = 0; i < DIM; ++i) {
            float m = inL[e * 69 + i];
            const float4 w = *reinterpret_cast<const float4*>(Ws + i * DIM + jg * 4);
            ax = fmaf(m, w.x, ax);
            ay = fmaf(m, w.y, ay);
            az = fmaf(m, w.z, az);
            aw = fmaf(m, w.w, aw);
        }
        outL[e * 69 + jg * 4 + 0] = fmaxf(ax, 0.0f);
        outL[e * 69 + jg * 4 + 1] = fmaxf(ay, 0.0f);
        outL[e * 69 + jg * 4 + 2] = fmaxf(az, 0.0f);
        outL[e * 69 + jg * 4 + 3] = fmaxf(aw, 0.0f);
    }
}

__global__ __launch_bounds__(256) void mlp_kernel(
    const float* __restrict__ x, const float* __restrict__ pos,
    const float* __restrict__ norm,
    const float* __restrict__ W1, const float* __restrict__ b1,
    const float* __restrict__ W2, const float* __restrict__ b2,
    const float* __restrict__ W3, const float* __restrict__ b3,
    const int* __restrict__ idx_ws, const float* __restrict__ pos_s_ws,
    const int* __restrict__ nbr_ws, const int* __restrict__ nvalid_ws,
    float* __restrict__ out)
{
    __shared__ alignas(16) float W1s[DIM * DIM];
    __shared__ alignas(16) float W2s[DIM * DIM];
    __shared__ float b1s[DIM], b2s[DIM];
    __shared__ float msgL[64 * 69];   // msg, later reused as h2
    __shared__ float h1L[64 * 69];
    __shared__ float aggL[2 * DIM];
    __shared__ int   nvL[2], jLs[64];

    const int t = threadIdx.x;
    const int cg0 = blockIdx.x * 2;

    for (int u = t; u < DIM * DIM; u += 256) { W1s[u] = W1[u]; W2s[u] = W2[u]; }
    if (t < DIM) { b1s[t] = b1[t]; b2s[t] = b2[t]; }
    if (t < 2) nvL[t] = min(nvalid_ws[cg0 + t], KNB);
    __syncthreads();

    const int e = t & 63, fc = t >> 6;
    const int lc = e >> 5, slot = e & 31;
    const int c = cg0 + lc;
    const int b = c >> 10;

    if (fc == 0) {
        int nv = nvL[lc];
        jLs[e] = (slot < nv) ? nbr_ws[c * KNB + slot] : 0;
    }
    __syncthreads();

    const int j = jLs[e];
    // gather x_j (each thread: 16 features of its edge)
    {
        const float* xj = x + ((size_t)b * NN + j) * NIN + fc * 16;
#pragma unroll
        for (int r = 0; r < 4; ++r) {
            float4 v = *reinterpret_cast<const float4*>(xj + r * 4);
            msgL[e * 69 + fc * 16 + r * 4 + 0] = v.x;
            msgL[e * 69 + fc * 16 + r * 4 + 1] = v.y;
            msgL[e * 69 + fc * 16 + r * 4 + 2] = v.z;
            msgL[e * 69 + fc * 16 + r * 4 + 3] = v.w;
        }
    }
    // point-pair features (one thread per edge)
    if (fc == 0) {
        float pix = pos_s_ws[c * 3 + 0];
        float piy = pos_s_ws[c * 3 + 1];
        float piz = pos_s_ws[c * 3 + 2];
        int ic = idx_ws[c];
        const float* pj_ = pos  + ((size_t)b * NN + j) * 3;
        const float* nj_ = norm + ((size_t)b * NN + j) * 3;
        const float* ni_ = norm + ((size_t)b * NN + ic) * 3;
        float dx = pj_[0] - pix, dy = pj_[1] - piy, dz = pj_[2] - piz;
        float nix = ni_[0], niy = ni_[1], niz = ni_[2];
        float njx = nj_[0], njy = nj_[1], njz = nj_[2];
        msgL[e * 69 + 64] = sqrtf(dx * dx + dy * dy + dz * dz);
        msgL[e * 69 + 65] = angle3(nix, niy, niz, dx, dy, dz);
        msgL[e * 69 + 66] = angle3(njx, njy, njz, dx, dy, dz);
        msgL[e * 69 + 67] = angle3(nix, niy, niz, njx, njy, njz);
    }
    __syncthreads();

    layer_pass(msgL, W1s, b1s, h1L, t);
    __syncthreads();
    layer_pass(h1L, W2s, b2s, msgL, t);   // h2 -> msgL
    __syncthreads();

    // masked max aggregation over valid slots
    if (t < 2 * DIM) {
        int cc = t / DIM, jf = t % DIM;
        int nv = nvL[cc];
        float v = -INFINITY;
        for (int s = 0; s < nv; ++s)
            v = fmaxf(v, msgL[(cc * 32 + s) * 69 + jf]);
        aggL[cc * DIM + jf] = v;
    }
    __syncthreads();

    // out = relu(agg @ W3 + b3)
    {
        int cc = t >> 7, o = t & 127;
        int cgl = cg0 + cc;
        float acc = b3[o];
#pragma unroll 4
        for (int i = 0; i < DIM; ++i)
            acc = fmaf(aggL[cc * DIM + i], W3[i * NOUTF + o], acc);
        out[(size_t)cgl * NOUTF + o] = fmaxf(acc, 0.0f);
    }
}

// ---------------------------------------------------------------------------
extern "C" void kernel_launch(void* const* d_in, const int* in_sizes, int n_in,
                              void* d_out, int out_size, void* d_ws, size_t ws_size,
                              hipStream_t stream)
{
    const float* x    = (const float*)d_in[0];
    const float* pos  = (const float*)d_in[1];
    const float* norm = (const float*)d_in[2];
    // d_in[3] = batch (unused, implicit in layout)
    const float* W1 = (const float*)d_in[4];
    const float* b1 = (const float*)d_in[5];
    const float* W2 = (const float*)d_in[6];
    const float* b2 = (const float*)d_in[7];
    const float* W3 = (const float*)d_in[8];
    const float* b3 = (const float*)d_in[9];

    float* out       = (float*)d_out;                       // [B*M*128]
    float* out_pos_s = out + (size_t)BB * MM * NOUTF;       // [B*M*3]
    float* out_idx   = out_pos_s + (size_t)BB * MM * 3;     // [B*M]

    char* ws = (char*)d_ws;
    int*   idx_ws    = (int*)ws;                                    // B*M
    float* pos_s_ws  = (float*)(ws + 32768);                        // B*M*3
    int*   nbr_ws    = (int*)(ws + 131072);                         // B*M*K
    int*   nvalid_ws = (int*)(ws + 131072 + (size_t)BB * MM * KNB * 4);

    fps_kernel<<<dim3(BB), dim3(512), 0, stream>>>(pos, idx_ws, pos_s_ws,
                                                   out_pos_s, out_idx);
    radius_kernel<<<dim3((BB * MM) / 4), dim3(256), 0, stream>>>(pos, pos_s_ws,
                                                                 nbr_ws, nvalid_ws);
    mlp_kernel<<<dim3((BB * MM) / 2), dim3(256), 0, stream>>>(
        x, pos, norm, W1, b1, W2, b2, W3, b3,
        idx_ws, pos_s_ws, nbr_ws, nvalid_ws, out);
}